// Round 1
// baseline (568.412 us; speedup 1.0000x reference)
//
#include <hip/hip_runtime.h>
#include <math.h>

#define HFD 64
#define WFD 64
#define NPIX 4096
#define CIN 1280
#define CCAP 256
#define NCAPS 19
#define DK 64
#define DV 16
#define BB 8
#define NI 32
#define PP 256
#define NOUT 84   // 81 useful outputs padded to 4*21
#define OG_N 21

// workspace layout (in floats)
#define WF_OFF   0
#define WF_SZ    (CIN*NOUT)            // 107520
#define BIAS_OFF (WF_OFF + WF_SZ)      // 107520
#define K_OFF    107648                // aligned
#define K_SZ     (BB*NPIX*DK)          // 2097152
#define V_OFF    (K_OFF + K_SZ)        // 2204800
#define V_SZ     (BB*NPIX*DV)          // 524288
#define A_OFF    (V_OFF + V_SZ)        // 2729088

// ---------------- Kernel 1: fold weights ----------------
// Wf[c][o] : o<64 -> (Wp^T Wk[:256])[c][o] ; 64..79 -> (Wp^T Wv[:256]) ; 80 -> Wa[0][c] ; 81..83 -> 0
// bias[o]  : o<64 -> bk[o] + bp.Wk[:,o]   ; 64..79 -> bv + bp.Wv    ; 80 -> ba[0]
__global__ void fold_kernel(const float* __restrict__ Wp, const float* __restrict__ bp,
                            const float* __restrict__ Wa, const float* __restrict__ ba,
                            const float* __restrict__ Wk, const float* __restrict__ bk,
                            const float* __restrict__ Wv, const float* __restrict__ bv,
                            float* __restrict__ ws) {
    int o = threadIdx.x;           // 0..83
    int blk = blockIdx.x;
    if (blk < CIN) {
        int c = blk;
        float acc = 0.f;
        if (o < DK) {
            for (int q = 0; q < CCAP; ++q) acc += Wp[q * CIN + c] * Wk[q * DK + o];
        } else if (o < DK + DV) {
            int od = o - DK;
            for (int q = 0; q < CCAP; ++q) acc += Wp[q * CIN + c] * Wv[q * DV + od];
        } else if (o == 80) {
            acc = Wa[c];           // row 0 of Wa
        }
        ws[WF_OFF + c * NOUT + o] = acc;
    } else {
        float acc = 0.f;
        if (o < DK) {
            acc = bk[o];
            for (int q = 0; q < CCAP; ++q) acc += bp[q] * Wk[q * DK + o];
        } else if (o < DK + DV) {
            int od = o - DK;
            acc = bv[od];
            for (int q = 0; q < CCAP; ++q) acc += bp[q] * Wv[q * DV + od];
        } else if (o == 80) {
            acc = ba[0];
        }
        ws[BIAS_OFF + o] = acc;
    }
}

// ---------------- Kernel 2: base maps GEMM ----------------
// Out[b,p,0:81] = X[b,:,p] . Wf + bias   (K=1280)
// block = 256 threads = 4 waves; wave og handles outputs [og*21, og*21+21), 64 pixels.
#define CK 16
__global__ __launch_bounds__(256) void base_gemm_kernel(const float* __restrict__ X,
                                                        float* __restrict__ ws) {
    __shared__ float xs[CK][64];
    int tid = threadIdx.x;
    int b = blockIdx.x >> 6;
    int p0 = (blockIdx.x & 63) << 6;
    int og = __builtin_amdgcn_readfirstlane(tid >> 6);
    int pl = tid & 63;

    const float* bias = ws + BIAS_OFF;
    float acc[OG_N];
#pragma unroll
    for (int k = 0; k < OG_N; ++k) acc[k] = bias[og * OG_N + k];

    const float* Xb = X + (size_t)b * CIN * NPIX + p0;
    const float* Wf = ws + WF_OFF;

    for (int c0 = 0; c0 < CIN; c0 += CK) {
        __syncthreads();
#pragma unroll
        for (int q = 0; q < (CK * 64) / 256; ++q) {
            int idx = q * 256 + tid;
            int cc = idx >> 6, pp = idx & 63;
            xs[cc][pp] = Xb[(size_t)(c0 + cc) * NPIX + pp];
        }
        __syncthreads();
#pragma unroll
        for (int cc = 0; cc < CK; ++cc) {
            float x = xs[cc][pl];
            const float* w = Wf + (c0 + cc) * NOUT + og * OG_N;
#pragma unroll
            for (int k = 0; k < OG_N; ++k) acc[k] += x * w[k];
        }
    }

    int p = p0 + pl;
    float* Kb = ws + K_OFF + (size_t)(b * NPIX + p) * DK;
    float* Vb = ws + V_OFF + (size_t)(b * NPIX + p) * DV;
    float* Ab = ws + A_OFF + b * NPIX + p;
#pragma unroll
    for (int k = 0; k < OG_N; ++k) {
        int o = og * OG_N + k;
        if (o < DK) Kb[o] = acc[k];
        else if (o < DK + DV) Vb[o - DK] = acc[k];
        else if (o == 80) Ab[0] = acc[k];
    }
}

// ---------------- Kernel 3: routing attention ----------------
// one block per (b,i) instance; 256 threads.
__global__ __launch_bounds__(256) void route_kernel(const float* __restrict__ ws,
                                                    const int* __restrict__ pts,
                                                    const float* __restrict__ Q,
                                                    const float* __restrict__ Wk,
                                                    const float* __restrict__ Wv,
                                                    const float* __restrict__ Wl,
                                                    const float* __restrict__ bl,
                                                    float* __restrict__ out) {
    __shared__ unsigned int bm[128];
    __shared__ int cnt_s[128];
    __shared__ int off_s[128];
    __shared__ int sy_s[128], sx_s[128];
    __shared__ unsigned short cells[PP];
    __shared__ float scores[NCAPS * PP];
    __shared__ float vmat[PP * DV];
    __shared__ float Qs[NCAPS * DK];
    __shared__ float wkr[2 * DK];
    __shared__ float wvr[2 * DV];
    __shared__ float denom_s[NCAPS];
    __shared__ float op_s[NCAPS * DV];
    __shared__ int n_s;
    __shared__ float mean_s[2];

    int tid = threadIdx.x;
    int bi = blockIdx.x;
    int b = bi >> 5;

    if (tid < 128) bm[tid] = 0u;
    for (int i = tid; i < NCAPS * DK; i += 256) Qs[i] = Q[i];
    if (tid < 2 * DK) wkr[tid] = Wk[(CCAP + (tid >> 6)) * DK + (tid & 63)];
    if (tid < 2 * DV) wvr[tid] = Wv[(CCAP + (tid >> 4)) * DV + (tid & 15)];
    __syncthreads();

    const int* pb = pts + (size_t)bi * 2 * PP;
    int y = pb[tid] >> 4;
    int x = pb[PP + tid] >> 4;
    int key = (y << 6) | x;
    atomicOr(&bm[key >> 5], 1u << (key & 31));
    __syncthreads();

    if (tid < 128) {
        unsigned int w = bm[tid];
        cnt_s[tid] = __popc(w);
        int sy = 0, sx = 0;
        unsigned int ww = w;
        while (ww) {
            int bit = __ffs(ww) - 1;
            ww &= ww - 1;
            int cell = (tid << 5) | bit;
            sy += cell >> 6;
            sx += cell & 63;
        }
        sy_s[tid] = sy;
        sx_s[tid] = sx;
        off_s[tid] = cnt_s[tid];
    }
    __syncthreads();
    // Hillis-Steele inclusive scan over 128 counts
    for (int d = 1; d < 128; d <<= 1) {
        int v = 0;
        if (tid < 128 && tid >= d) v = off_s[tid - d];
        __syncthreads();
        if (tid < 128) off_s[tid] += v;
        __syncthreads();
    }
    if (tid == 0) {
        n_s = off_s[127];
        int sy = 0, sx = 0;
        for (int i = 0; i < 128; ++i) { sy += sy_s[i]; sx += sx_s[i]; }
        int n = n_s; if (n < 1) n = 1;
        mean_s[0] = (float)sy / (float)n;
        mean_s[1] = (float)sx / (float)n;
    }
    // compact set cells into list
    if (tid < 128) {
        int off = off_s[tid] - cnt_s[tid];
        unsigned int ww = bm[tid];
        while (ww) {
            int bit = __ffs(ww) - 1;
            ww &= ww - 1;
            cells[off++] = (unsigned short)((tid << 5) | bit);
        }
    }
    __syncthreads();

    int n = n_s;
    float mean_y = mean_s[0], mean_x = mean_s[1];

    if (tid < n) {
        int cell = cells[tid];
        int yc = cell >> 6, xc = cell & 63;
        float r0 = ((float)yc - mean_y) * (1.f / 64.f);
        float r1 = ((float)xc - mean_x) * (1.f / 64.f);
        const float* Kb = ws + K_OFF + (size_t)(b * NPIX + cell) * DK;
        float kv[DK];
#pragma unroll
        for (int d = 0; d < DK; ++d) kv[d] = Kb[d] + r0 * wkr[d] + r1 * wkr[DK + d];
        float z = ws[A_OFF + b * NPIX + cell];
        float a = 1.f / (1.f + expf(-z));
        float la = logf(a + 1e-6f);
#pragma unroll 1
        for (int c = 0; c < NCAPS; ++c) {
            float acc = 0.f;
#pragma unroll
            for (int d = 0; d < DK; ++d) acc += Qs[c * DK + d] * kv[d];
            scores[c * PP + tid] = acc * 0.125f + la;
        }
        const float* Vb = ws + V_OFF + (size_t)(b * NPIX + cell) * DV;
#pragma unroll
        for (int d = 0; d < DV; ++d) vmat[tid * DV + d] = Vb[d] + r0 * wvr[d] + r1 * wvr[DV + d];
    }
    __syncthreads();

    // wave-parallel softmax: wave w handles rows w, w+4, ...
    int wave = tid >> 6, lane = tid & 63;
    for (int c = wave; c < NCAPS; c += 4) {
        float v4[4];
        float m = -1e30f;
#pragma unroll
        for (int q = 0; q < 4; ++q) {
            int j = lane + q * 64;
            float s = (j < n) ? scores[c * PP + j] : -1e30f;
            v4[q] = s;
            m = fmaxf(m, s);
        }
#pragma unroll
        for (int d = 32; d >= 1; d >>= 1) m = fmaxf(m, __shfl_xor(m, d, 64));
        float sum = 0.f;
#pragma unroll
        for (int q = 0; q < 4; ++q) {
            int j = lane + q * 64;
            if (j < n) {
                float e = expf(v4[q] - m);
                scores[c * PP + j] = e;
                sum += e;
            }
        }
#pragma unroll
        for (int d = 32; d >= 1; d >>= 1) sum += __shfl_xor(sum, d, 64);
        if (lane == 0) denom_s[c] = sum;
    }
    __syncthreads();

    // PV: out_poses[c][d] = sum_j attn * v
    for (int c = tid >> 4; c < NCAPS; c += 16) {
        int d = tid & 15;
        float acc = 0.f;
        for (int j = 0; j < n; ++j) acc += scores[c * PP + j] * vmat[j * DV + d];
        op_s[c * DV + d] = acc / denom_s[c];
    }
    __syncthreads();

    if (tid < NCAPS) {
        float acc = bl[0];
#pragma unroll
        for (int d = 0; d < DV; ++d) acc += op_s[tid * DV + d] * Wl[d];
        out[bi * NCAPS + tid] = 1.f / (1.f + expf(-acc));
    }
}

extern "C" void kernel_launch(void* const* d_in, const int* in_sizes, int n_in,
                              void* d_out, int out_size, void* d_ws, size_t ws_size,
                              hipStream_t stream) {
    const float* X  = (const float*)d_in[0];
    const float* Wp = (const float*)d_in[1];
    const float* bp = (const float*)d_in[2];
    const float* Wa = (const float*)d_in[3];
    const float* ba = (const float*)d_in[4];
    const float* Q  = (const float*)d_in[5];
    const float* Wk = (const float*)d_in[6];
    const float* bk = (const float*)d_in[7];
    const float* Wv = (const float*)d_in[8];
    const float* bv = (const float*)d_in[9];
    const float* Wl = (const float*)d_in[10];
    const float* bl = (const float*)d_in[11];
    const int* pts  = (const int*)d_in[12];
    float* out = (float*)d_out;
    float* ws = (float*)d_ws;

    hipLaunchKernelGGL(fold_kernel, dim3(CIN + 1), dim3(NOUT), 0, stream,
                       Wp, bp, Wa, ba, Wk, bk, Wv, bv, ws);
    hipLaunchKernelGGL(base_gemm_kernel, dim3(512), dim3(256), 0, stream, X, ws);
    hipLaunchKernelGGL(route_kernel, dim3(BB * NI), dim3(256), 0, stream,
                       ws, pts, Q, Wk, Wv, Wl, bl, out);
}

// Round 4
// 391.210 us; speedup vs baseline: 1.4530x; 1.4530x over previous
//
#include <hip/hip_runtime.h>
#include <math.h>

#define CIN 1280
#define NPIX 4096
#define NCAPS 19
#define BB 8
#define NI 32
#define PP 256
#define NOUT 21     // 19 score-logits + 1 v-scalar + 1 act-logit
#define WROW 24     // padded row stride for Wbig / A

// workspace layout (float offsets)
#define A_OFF     0          // 256 x WROW
#define WBIG_OFF  6144       // 1280 x WROW
#define CONST_OFF 36864      // 128
#define MAP_OFF   40960      // 21 planes x 32768
#define MAP_PLANE 32768      // BB*NPIX
#define MAP_SZ    (NOUT * MAP_PLANE)

// const slots
#define C_BIAS  0    // [19]
#define C_QW0   32   // [19]
#define C_QW1   64   // [19]
#define C_BIASV 96
#define C_UV0   97
#define C_UV1   98
#define C_BA0   99
#define C_BL    100

// ---------- zero the accumulation map (graph-capture-safe, no memset) ----------
__global__ __launch_bounds__(256) void zero_map_kernel(float4* __restrict__ map4) {
    int i = blockIdx.x * 256 + threadIdx.x;
    int n4 = MAP_SZ / 4;
    for (; i < n4; i += gridDim.x * 256) map4[i] = make_float4(0.f, 0.f, 0.f, 0.f);
}

// ---------- fold stage A: A[o][c] = (Wk[o]·Q[c])/8 (c<19), A[o][19] = Wv[o]·Wl ----------
__global__ __launch_bounds__(256) void foldA_kernel(const float* __restrict__ Wk,
                                                    const float* __restrict__ Q,
                                                    const float* __restrict__ Wv,
                                                    const float* __restrict__ Wl,
                                                    float* __restrict__ ws) {
    __shared__ float Qs[NCAPS * 64];
    int tid = threadIdx.x;
    for (int i = tid; i < NCAPS * 64; i += 256) Qs[i] = Q[i];
    __syncthreads();
    float wkr[64];
#pragma unroll
    for (int d = 0; d < 64; ++d) wkr[d] = Wk[tid * 64 + d];
    float* Ar = ws + A_OFF + tid * WROW;
#pragma unroll 1
    for (int c = 0; c < NCAPS; ++c) {
        float s = 0.f;
#pragma unroll
        for (int d = 0; d < 64; ++d) s += wkr[d] * Qs[c * 64 + d];
        Ar[c] = 0.125f * s;
    }
    float u = 0.f;
#pragma unroll
    for (int d = 0; d < 16; ++d) u += Wv[tid * 16 + d] * Wl[d];
    Ar[19] = u;
}

// ---------- fold stage B: Wbig[ci][k] = sum_o Wp[o][ci]*A[o][k]; col20 = Wa[ci]; + consts ----------
__global__ __launch_bounds__(256) void foldB_kernel(const float* __restrict__ Wp,
                                                    const float* __restrict__ bp,
                                                    const float* __restrict__ Wa,
                                                    const float* __restrict__ ba,
                                                    const float* __restrict__ Wk,
                                                    const float* __restrict__ bk,
                                                    const float* __restrict__ Wv,
                                                    const float* __restrict__ bv,
                                                    const float* __restrict__ Q,
                                                    const float* __restrict__ Wl,
                                                    const float* __restrict__ bl,
                                                    const float* __restrict__ A,
                                                    float* __restrict__ wbig,
                                                    float* __restrict__ cst) {
    int tid = threadIdx.x;
    if (blockIdx.x < 5) {
        int ci = blockIdx.x * 256 + tid;
        float acc[20];
#pragma unroll
        for (int k = 0; k < 20; ++k) acc[k] = 0.f;
#pragma unroll 1
        for (int o = 0; o < 256; ++o) {
            float wp = Wp[(size_t)o * CIN + ci];
            const float* ar = A + o * WROW;
#pragma unroll
            for (int k = 0; k < 20; ++k) acc[k] = fmaf(wp, ar[k], acc[k]);
        }
        float* wrow = wbig + ci * WROW;
#pragma unroll
        for (int k = 0; k < 20; ++k) wrow[k] = acc[k];
        wrow[20] = Wa[ci];   // row 0 of Wa
    } else {
        if (tid < NCAPS) {
            float s = 0.f;
            for (int o = 0; o < 256; ++o) s += bp[o] * A[o * WROW + tid];
            float qb = 0.f, q0 = 0.f, q1 = 0.f;
            for (int d = 0; d < 64; ++d) {
                float qv = Q[tid * 64 + d];
                qb += qv * bk[d];
                q0 += qv * Wk[256 * 64 + d];
                q1 += qv * Wk[257 * 64 + d];
            }
            cst[C_BIAS + tid] = s + 0.125f * qb;
            cst[C_QW0 + tid]  = 0.125f * q0;
            cst[C_QW1 + tid]  = 0.125f * q1;
        } else if (tid == 32) {
            float s = 0.f;
            for (int o = 0; o < 256; ++o) s += bp[o] * A[o * WROW + 19];
            float t = 0.f;
            for (int d = 0; d < 16; ++d) t += bv[d] * Wl[d];
            cst[C_BIASV] = s + t;
        } else if (tid == 33) {
            float t = 0.f;
            for (int d = 0; d < 16; ++d) t += Wv[256 * 16 + d] * Wl[d];
            cst[C_UV0] = t;
        } else if (tid == 34) {
            float t = 0.f;
            for (int d = 0; d < 16; ++d) t += Wv[257 * 16 + d] * Wl[d];
            cst[C_UV1] = t;
        } else if (tid == 35) {
            cst[C_BA0] = ba[0];
            cst[C_BL]  = bl[0];
        }
    }
}

// ---------- base maps: map[k][pixg] += X[:,pix]·Wbig[:,k]  (K-split x8, no LDS, no barriers) ----------
#define KSPLIT 8
#define KC (CIN / KSPLIT)   // 160
__global__ __launch_bounds__(256) void base_gemm_kernel(const float* __restrict__ X,
                                                        const float* __restrict__ wbig,
                                                        float* __restrict__ map) {
    int tid = threadIdx.x;
    int bp = blockIdx.x & 127;
    int ks = blockIdx.x >> 7;
    int pixg = (bp << 8) | tid;
    int b = pixg >> 12;
    int p = pixg & (NPIX - 1);
    const float* Xc = X + (size_t)b * CIN * NPIX + (size_t)(ks * KC) * NPIX + p;
    const float* Wb = wbig + ks * KC * WROW;
    float acc[NOUT];
#pragma unroll
    for (int k = 0; k < NOUT; ++k) acc[k] = 0.f;
#pragma unroll 1
    for (int c0 = 0; c0 < KC; c0 += 8) {
        float xr[8];
#pragma unroll
        for (int i = 0; i < 8; ++i) xr[i] = Xc[(size_t)(c0 + i) * NPIX];
        const float* w = Wb + c0 * WROW;
#pragma unroll
        for (int i = 0; i < 8; ++i) {
#pragma unroll
            for (int k = 0; k < NOUT; ++k) acc[k] = fmaf(xr[i], w[i * WROW + k], acc[k]);
        }
    }
    float* mp = map + pixg;
#pragma unroll
    for (int k = 0; k < NOUT; ++k) atomicAdd(mp + k * MAP_PLANE, acc[k]);
}

// ---------- routing: bitmap-unique + mean + scores + fused softmax/PV ----------
__global__ __launch_bounds__(256) void route_kernel(const float* __restrict__ map,
                                                    const float* __restrict__ cstg,
                                                    const int* __restrict__ pts,
                                                    float* __restrict__ out) {
    __shared__ unsigned bm[128];
    __shared__ int cnt_s[128], off_s[128], sy_s[128], sx_s[128];
    __shared__ unsigned short cells[PP];
    __shared__ float esc[NCAPS][PP];
    __shared__ float vj[PP];
    __shared__ float cst[128];
    __shared__ int n_s;
    __shared__ float mean_s[2];

    int tid = threadIdx.x;
    int bi = blockIdx.x;
    int b = bi >> 5;

    if (tid < 128) { bm[tid] = 0u; cst[tid] = cstg[tid]; }
    __syncthreads();

    const int* pb = pts + (size_t)bi * 2 * PP;
    int y = pb[tid] >> 4;
    int x = pb[PP + tid] >> 4;
    int key = (y << 6) | x;
    atomicOr(&bm[key >> 5], 1u << (key & 31));
    __syncthreads();

    if (tid < 128) {
        unsigned w = bm[tid];
        int cnt = __popc(w);
        int sy = 0, sx = 0;
        unsigned ww = w;
        while (ww) {
            int bit = __ffs(ww) - 1;
            ww &= ww - 1;
            int cell = (tid << 5) | bit;
            sy += cell >> 6;
            sx += cell & 63;
        }
        cnt_s[tid] = cnt; off_s[tid] = cnt; sy_s[tid] = sy; sx_s[tid] = sx;
    }
    __syncthreads();
    for (int d = 1; d < 128; d <<= 1) {
        int v = 0;
        if (tid < 128 && tid >= d) v = off_s[tid - d];
        __syncthreads();
        if (tid < 128) off_s[tid] += v;
        __syncthreads();
    }
    if (tid < 64) {
        int ry = sy_s[tid] + sy_s[tid + 64];
        int rx = sx_s[tid] + sx_s[tid + 64];
#pragma unroll
        for (int d = 32; d >= 1; d >>= 1) { ry += __shfl_xor(ry, d, 64); rx += __shfl_xor(rx, d, 64); }
        if (tid == 0) {
            int n = off_s[127];
            n_s = n;
            float fn = (float)(n > 0 ? n : 1);
            mean_s[0] = (float)ry / fn;
            mean_s[1] = (float)rx / fn;
        }
    }
    if (tid < 128) {
        int off = off_s[tid] - cnt_s[tid];
        unsigned ww = bm[tid];
        while (ww) {
            int bit = __ffs(ww) - 1;
            ww &= ww - 1;
            cells[off++] = (unsigned short)((tid << 5) | bit);
        }
    }
    __syncthreads();

    int n = n_s;
    if (tid < n) {
        int cell = cells[tid];
        int yc = cell >> 6, xc = cell & 63;
        float r0 = ((float)yc - mean_s[0]) * (1.f / 64.f);
        float r1 = ((float)xc - mean_s[1]) * (1.f / 64.f);
        const float* mp = map + b * NPIX + cell;
        float z = mp[20 * MAP_PLANE] + cst[C_BA0];
        float a = 1.f / (1.f + expf(-z));
        float la = logf(a + 1e-6f);
        vj[tid] = mp[19 * MAP_PLANE] + cst[C_BIASV] + r0 * cst[C_UV0] + r1 * cst[C_UV1];
#pragma unroll
        for (int c = 0; c < NCAPS; ++c) {
            esc[c][tid] = mp[c * MAP_PLANE] + cst[C_BIAS + c] + r0 * cst[C_QW0 + c]
                        + r1 * cst[C_QW1 + c] + la;
        }
    }
    __syncthreads();

    int wave = tid >> 6, lane = tid & 63;
    for (int c = wave; c < NCAPS; c += 4) {
        float ss[4];
        float m = -1e30f;
#pragma unroll
        for (int q = 0; q < 4; ++q) {
            int j = lane + q * 64;
            ss[q] = (j < n) ? esc[c][j] : -1e30f;
            m = fmaxf(m, ss[q]);
        }
#pragma unroll
        for (int d = 32; d >= 1; d >>= 1) m = fmaxf(m, __shfl_xor(m, d, 64));
        float se = 0.f, sev = 0.f;
#pragma unroll
        for (int q = 0; q < 4; ++q) {
            int j = lane + q * 64;
            if (j < n) {
                float e = expf(ss[q] - m);
                se += e;
                sev += e * vj[j];
            }
        }
#pragma unroll
        for (int d = 32; d >= 1; d >>= 1) { se += __shfl_xor(se, d, 64); sev += __shfl_xor(sev, d, 64); }
        if (lane == 0) {
            float logit = sev / se + cst[C_BL];
            out[bi * NCAPS + c] = 1.f / (1.f + expf(-logit));
        }
    }
}

extern "C" void kernel_launch(void* const* d_in, const int* in_sizes, int n_in,
                              void* d_out, int out_size, void* d_ws, size_t ws_size,
                              hipStream_t stream) {
    const float* X  = (const float*)d_in[0];
    const float* Wp = (const float*)d_in[1];
    const float* bp = (const float*)d_in[2];
    const float* Wa = (const float*)d_in[3];
    const float* ba = (const float*)d_in[4];
    const float* Q  = (const float*)d_in[5];
    const float* Wk = (const float*)d_in[6];
    const float* bk = (const float*)d_in[7];
    const float* Wv = (const float*)d_in[8];
    const float* bv = (const float*)d_in[9];
    const float* Wl = (const float*)d_in[10];
    const float* bl = (const float*)d_in[11];
    const int* pts  = (const int*)d_in[12];
    float* out = (float*)d_out;
    float* ws  = (float*)d_ws;

    hipLaunchKernelGGL(zero_map_kernel, dim3(512), dim3(256), 0, stream,
                       (float4*)(ws + MAP_OFF));
    hipLaunchKernelGGL(foldA_kernel, dim3(1), dim3(256), 0, stream, Wk, Q, Wv, Wl, ws);
    hipLaunchKernelGGL(foldB_kernel, dim3(6), dim3(256), 0, stream,
                       Wp, bp, Wa, ba, Wk, bk, Wv, bv, Q, Wl, bl,
                       ws + A_OFF, ws + WBIG_OFF, ws + CONST_OFF);
    hipLaunchKernelGGL(base_gemm_kernel, dim3(128 * KSPLIT), dim3(256), 0, stream,
                       X, ws + WBIG_OFF, ws + MAP_OFF);
    hipLaunchKernelGGL(route_kernel, dim3(BB * NI), dim3(256), 0, stream,
                       ws + MAP_OFF, ws + CONST_OFF, pts, out);
}